// Round 4
// baseline (781.987 us; speedup 1.0000x reference)
//
#include <hip/hip_runtime.h>
#include <cmath>

#define TT 16
#define BB 16
#define NN 1024
#define EE 16384
#define FIN 128
#define MIDC 16
#define HH 256
#define KK 820
#define HS 20           // hbuf row stride in floats (80 B, 16 B aligned for ds_read_b128)

// ---- LDS float-slot layout for k_graph ----
#define OFF_HBUF   0
#define N_HBUF     (NN*HS)                    // 20480
#define OFF_CSR    (OFF_HBUF + N_HBUF)        // ushort[EE] -> 8192 float slots (reused as partials[16][256] at the end)
#define N_CSR      (EE/2)
#define OFF_HEAD   (OFF_CSR + N_CSR)          // int[NN+1]
#define OFF_CUR    (OFF_HEAD + NN + 1)        // int[NN]
#define OFF_SCANA  (OFF_CUR + NN)             // int[NN]
#define OFF_DINV   (OFF_SCANA + NN)           // float[NN] (aliases scanB during the prefix scan)
#define OFF_UB     (OFF_DINV + NN)            // uint[NN] kept mask
#define OFF_HIST   (OFF_UB + NN)              // int[256]
#define OFF_S      (OFF_HIST + 256)           // int[256] suffix sums
#define OFF_WCNT   (OFF_S + 256)              // int[16]
#define OFF_CTRL   (OFF_WCNT + 16)            // int[8]
#define SM_FLOATS  (OFF_CTRL + 8)
#define SM_BYTES   (SM_FLOATS * 4)            // ~137.3 KB

__device__ __forceinline__ unsigned bf16pair(float a, float b) {
  unsigned ua = __float_as_uint(a), ub_ = __float_as_uint(b);
  ua  = (ua  + 0x7FFFu + ((ua  >> 16) & 1u)) >> 16;
  ub_ = (ub_ + 0x7FFFu + ((ub_ >> 16) & 1u)) >> 16;
  return ua | (ub_ << 16);
}
__device__ __forceinline__ float bf16lo(unsigned p) { return __uint_as_float(p << 16); }
__device__ __forceinline__ float bf16hi(unsigned p) { return __uint_as_float(p & 0xFFFF0000u); }
__device__ __forceinline__ float dot4(float4 a, float4 b) {
  return a.x*b.x + a.y*b.y + a.z*b.z + a.w*b.w;
}

// ---------------------------------------------------------------------------
// K0: conv1 matmul for ALL graphs at high occupancy: h0 = x @ W1 (bf16-packed).
// 1024 blocks x 256 threads (8 blocks/CU): streams x at HBM rate.
// ---------------------------------------------------------------------------
__global__ __launch_bounds__(256) void k_conv1(
    const float* __restrict__ x, const float* __restrict__ W1,
    unsigned* __restrict__ h0)
{
  const int gid = blockIdx.x * 256 + threadIdx.x;     // global node id
  const float4* xr = (const float4*)(x + (size_t)gid * FIN);
  float acc[MIDC];
#pragma unroll
  for (int c = 0; c < MIDC; ++c) acc[c] = 0.0f;
  for (int k4 = 0; k4 < FIN/4; ++k4) {
    float4 v = xr[k4];
    const float* w0 = W1 + (k4*4 + 0)*MIDC;   // wave-uniform -> s_load
    const float* w1 = W1 + (k4*4 + 1)*MIDC;
    const float* w2 = W1 + (k4*4 + 2)*MIDC;
    const float* w3 = W1 + (k4*4 + 3)*MIDC;
#pragma unroll
    for (int c = 0; c < MIDC; ++c)
      acc[c] += v.x*w0[c] + v.y*w1[c] + v.z*w2[c] + v.w*w3[c];
  }
  uint4 q0, q1;
  q0.x = bf16pair(acc[0],  acc[1]);  q0.y = bf16pair(acc[2],  acc[3]);
  q0.z = bf16pair(acc[4],  acc[5]);  q0.w = bf16pair(acc[6],  acc[7]);
  q1.x = bf16pair(acc[8],  acc[9]);  q1.y = bf16pair(acc[10], acc[11]);
  q1.z = bf16pair(acc[12], acc[13]); q1.w = bf16pair(acc[14], acc[15]);
  uint4* o = (uint4*)h0;
  o[(size_t)gid*2 + 0] = q0;
  o[(size_t)gid*2 + 1] = q1;
}

// ---------------------------------------------------------------------------
// K1: one block per graph, 1024 threads (= N nodes). load h0 -> CSR build ->
// gather conv1 -> gather SAG -> radix top-K -> gate -> gather conv2 ->
// 16x256 matmul + relu + mean pool.  No float atomics anywhere.
// ---------------------------------------------------------------------------
__global__ __launch_bounds__(1024) void k_graph(
    const unsigned* __restrict__ h0, const int* __restrict__ ei,
    const float* __restrict__ b1,
    const float* __restrict__ Wl, const float* __restrict__ Wr,
    const float* __restrict__ bsag, const float* __restrict__ W2,
    const float* __restrict__ b2, float* __restrict__ emb)
{
  extern __shared__ __align__(16) float sm[];
  float4*         hb4   = (float4*)(sm + OFF_HBUF);
  unsigned short* csr   = (unsigned short*)(sm + OFF_CSR);
  int*            head  = (int*)(sm + OFF_HEAD);
  int*            cur   = (int*)(sm + OFF_CUR);
  int*            scanA = (int*)(sm + OFF_SCANA);
  int*            scanB = (int*)(sm + OFF_DINV);     // alias, freed before dinv use
  float*          dinvb = sm + OFF_DINV;
  unsigned*       ubv   = (unsigned*)(sm + OFF_UB);
  int*            hist  = (int*)(sm + OFF_HIST);
  int*            S     = (int*)(sm + OFF_S);
  int*            wcnt  = (int*)(sm + OFF_WCNT);
  int*            ctrl  = (int*)(sm + OFF_CTRL);

  const int g   = blockIdx.x;
  const int tid = threadIdx.x;
  const int*   srcp = ei + (size_t)g * (2*EE);
  const int*   dstp = srcp + EE;

  cur[tid] = 0;

  // ---- load conv1 result (bf16-packed, coalesced 32 B/lane) ----
  float hown[MIDC];
  {
    const uint4* hp = (const uint4*)h0 + (size_t)g * NN * 2;
    uint4 p0 = hp[tid*2], p1 = hp[tid*2 + 1];
    hown[0] = bf16lo(p0.x); hown[1] = bf16hi(p0.x);
    hown[2] = bf16lo(p0.y); hown[3] = bf16hi(p0.y);
    hown[4] = bf16lo(p0.z); hown[5] = bf16hi(p0.z);
    hown[6] = bf16lo(p0.w); hown[7] = bf16hi(p0.w);
    hown[8]  = bf16lo(p1.x); hown[9]  = bf16hi(p1.x);
    hown[10] = bf16lo(p1.y); hown[11] = bf16hi(p1.y);
    hown[12] = bf16lo(p1.z); hown[13] = bf16hi(p1.z);
    hown[14] = bf16lo(p1.w); hown[15] = bf16hi(p1.w);
    hb4[tid*5+0] = make_float4(hown[0],  hown[1],  hown[2],  hown[3]);
    hb4[tid*5+1] = make_float4(hown[4],  hown[5],  hown[6],  hown[7]);
    hb4[tid*5+2] = make_float4(hown[8],  hown[9],  hown[10], hown[11]);
    hb4[tid*5+3] = make_float4(hown[12], hown[13], hown[14], hown[15]);
  }
  __syncthreads();

  // ---- degree count (int atomics, native) ----
  for (int e = tid; e < EE; e += 1024) atomicAdd(&cur[dstp[e]], 1);
  __syncthreads();

  // ---- exclusive prefix scan (Hillis-Steele, ping-pong) ----
  {
    int v = cur[tid];
    scanA[tid] = v;
    __syncthreads();
    int* s_ = scanA; int* d_ = scanB;
    for (int off = 1; off < NN; off <<= 1) {
      int t = s_[tid];
      if (tid >= off) t += s_[tid - off];
      d_[tid] = t;
      __syncthreads();
      int* tmp = s_; s_ = d_; d_ = tmp;
    }
    int inc = s_[tid];
    int ex  = inc - v;
    __syncthreads();                 // all scan reads done before dinvb overwrite
    head[tid] = ex;
    cur[tid]  = ex;
    if (tid == 0) head[NN] = EE;
    dinvb[tid] = rsqrtf((float)(v + 1));
  }
  __syncthreads();

  // ---- CSR fill (src ids as ushort) ----
  for (int e = tid; e < EE; e += 1024) {
    int s = srcp[e], d = dstp[e];
    int pos = atomicAdd(&cur[d], 1);
    csr[pos] = (unsigned short)s;
  }
  __syncthreads();

  const int beg = head[tid], end = head[tid+1];

  // ---- gather conv1: acc = sum_s dinv_s * h_s ----
  float h1own[MIDC];
  {
    float accv[MIDC];
#pragma unroll
    for (int c = 0; c < MIDC; ++c) accv[c] = 0.0f;
    for (int p = beg; p < end; ++p) {
      int s = csr[p];
      float ds_ = dinvb[s];
      float4 a0 = hb4[s*5+0], a1 = hb4[s*5+1], a2 = hb4[s*5+2], a3 = hb4[s*5+3];
      accv[0]  += a0.x*ds_; accv[1]  += a0.y*ds_; accv[2]  += a0.z*ds_; accv[3]  += a0.w*ds_;
      accv[4]  += a1.x*ds_; accv[5]  += a1.y*ds_; accv[6]  += a1.z*ds_; accv[7]  += a1.w*ds_;
      accv[8]  += a2.x*ds_; accv[9]  += a2.y*ds_; accv[10] += a2.z*ds_; accv[11] += a2.w*ds_;
      accv[12] += a3.x*ds_; accv[13] += a3.y*ds_; accv[14] += a3.z*ds_; accv[15] += a3.w*ds_;
    }
    float di = dinvb[tid];
#pragma unroll
    for (int c = 0; c < MIDC; ++c)
      h1own[c] = fmaxf(di*accv[c] + hown[c]*di*di + b1[c], 0.0f);
  }
  __syncthreads();
  hb4[tid*5+0] = make_float4(h1own[0],  h1own[1],  h1own[2],  h1own[3]);
  hb4[tid*5+1] = make_float4(h1own[4],  h1own[5],  h1own[6],  h1own[7]);
  hb4[tid*5+2] = make_float4(h1own[8],  h1own[9],  h1own[10], h1own[11]);
  hb4[tid*5+3] = make_float4(h1own[12], h1own[13], h1own[14], h1own[15]);
  __syncthreads();

  // ---- gather SAG: agg = sum_s h1_s ; score ----
  float score;
  unsigned myu;
  {
    float aggv[MIDC];
#pragma unroll
    for (int c = 0; c < MIDC; ++c) aggv[c] = 0.0f;
    for (int p = beg; p < end; ++p) {
      int s = csr[p];
      float4 a0 = hb4[s*5+0], a1 = hb4[s*5+1], a2 = hb4[s*5+2], a3 = hb4[s*5+3];
      aggv[0]  += a0.x; aggv[1]  += a0.y; aggv[2]  += a0.z; aggv[3]  += a0.w;
      aggv[4]  += a1.x; aggv[5]  += a1.y; aggv[6]  += a1.z; aggv[7]  += a1.w;
      aggv[8]  += a2.x; aggv[9]  += a2.y; aggv[10] += a2.z; aggv[11] += a2.w;
      aggv[12] += a3.x; aggv[13] += a3.y; aggv[14] += a3.z; aggv[15] += a3.w;
    }
    score = bsag[0];
#pragma unroll
    for (int c = 0; c < MIDC; ++c) score += aggv[c]*Wl[c] + h1own[c]*Wr[c];
    unsigned ubits = __float_as_uint(score);
    myu = (ubits & 0x80000000u) ? ~ubits : (ubits | 0x80000000u);
  }

  // ---- radix select K-th largest key (parallel suffix scan per round) ----
  int remK = KK;
  unsigned pref = 0;
  for (int byte = 3; byte >= 0; --byte) {
    if (tid < 256) hist[tid] = 0;
    __syncthreads();
    const int sh = byte * 8;
    const unsigned hi_mask = (byte == 3) ? 0u : (0xFFFFFFFFu << (sh + 8));
    if ((myu & hi_mask) == pref) atomicAdd(&hist[(myu >> sh) & 255u], 1);
    __syncthreads();
    if (tid < 64) {
      int h0_ = hist[tid*4+0], h1_ = hist[tid*4+1], h2_ = hist[tid*4+2], h3_ = hist[tid*4+3];
      int s3 = h3_, s2 = h2_ + s3, s1 = h1_ + s2, s0 = h0_ + s1;
      int run = s0;
#pragma unroll
      for (int off = 1; off < 64; off <<= 1) {
        int o = __shfl_down(run, off);
        if (tid + off < 64) run += o;
      }
      int above = run - s0;
      S[tid*4+0] = above + s0;
      S[tid*4+1] = above + s1;
      S[tid*4+2] = above + s2;
      S[tid*4+3] = above + s3;
    }
    __syncthreads();
    if (tid < 256) {
      int Sv = S[tid];
      int Sn = (tid < 255) ? S[tid+1] : 0;
      if (Sv >= remK && Sn < remK) { ctrl[0] = remK - Sn; ctrl[1] = tid; }
    }
    __syncthreads();
    remK  = ctrl[0];
    pref |= ((unsigned)ctrl[1]) << sh;
    __syncthreads();
  }
  const unsigned vstar = pref;
  const int need = remK;

  // ---- kept mask: ties broken by lowest index (ballot-based count) ----
  {
    const int wid = tid >> 6, lane = tid & 63;
    bool eq = (myu == vstar);
    unsigned long long m = __ballot(eq);
    if (lane == 0) wcnt[wid] = __popcll(m);
    __syncthreads();
    int before = (lane == 0) ? 0 : __popcll(m & ((~0ull) >> (64 - lane)));
    for (int w = 0; w < wid; ++w) before += wcnt[w];
    int kept = (myu > vstar) ? 1 : (eq ? (before < need) : 0);
    float gate = kept ? tanhf(score) : 0.0f;
#pragma unroll
    for (int c = 0; c < MIDC; ++c) h1own[c] *= gate;    // h1own becomes xp (0 if dropped)
    hb4[tid*5+0] = make_float4(h1own[0],  h1own[1],  h1own[2],  h1own[3]);
    hb4[tid*5+1] = make_float4(h1own[4],  h1own[5],  h1own[6],  h1own[7]);
    hb4[tid*5+2] = make_float4(h1own[8],  h1own[9],  h1own[10], h1own[11]);
    hb4[tid*5+3] = make_float4(h1own[12], h1own[13], h1own[14], h1own[15]);
    ubv[tid] = (unsigned)kept;
  }
  __syncthreads();

  // ---- conv2 degree over valid edges; dinv2 ----
  float di2;
  {
    int cnt2 = 0;
    for (int p = beg; p < end; ++p) cnt2 += (int)ubv[csr[p]];
    di2 = rsqrtf((float)(1 + cnt2));
    dinvb[tid] = di2;           // old dinv has no remaining readers
  }
  __syncthreads();

  // ---- gather conv2 (xp already zero for dropped sources) ----
  {
    float acc2[MIDC];
#pragma unroll
    for (int c = 0; c < MIDC; ++c) acc2[c] = 0.0f;
    for (int p = beg; p < end; ++p) {
      int s = csr[p];
      float ds_ = dinvb[s];
      float4 a0 = hb4[s*5+0], a1 = hb4[s*5+1], a2 = hb4[s*5+2], a3 = hb4[s*5+3];
      acc2[0]  += a0.x*ds_; acc2[1]  += a0.y*ds_; acc2[2]  += a0.z*ds_; acc2[3]  += a0.w*ds_;
      acc2[4]  += a1.x*ds_; acc2[5]  += a1.y*ds_; acc2[6]  += a1.z*ds_; acc2[7]  += a1.w*ds_;
      acc2[8]  += a2.x*ds_; acc2[9]  += a2.y*ds_; acc2[10] += a2.z*ds_; acc2[11] += a2.w*ds_;
      acc2[12] += a3.x*ds_; acc2[13] += a3.y*ds_; acc2[14] += a3.z*ds_; acc2[15] += a3.w*ds_;
    }
#pragma unroll
    for (int c = 0; c < MIDC; ++c)
      h1own[c] = di2*acc2[c] + h1own[c]*di2*di2;        // pre2
  }
  __syncthreads();
  hb4[tid*5+0] = make_float4(h1own[0],  h1own[1],  h1own[2],  h1own[3]);
  hb4[tid*5+1] = make_float4(h1own[4],  h1own[5],  h1own[6],  h1own[7]);
  hb4[tid*5+2] = make_float4(h1own[8],  h1own[9],  h1own[10], h1own[11]);
  hb4[tid*5+3] = make_float4(h1own[12], h1own[13], h1own[14], h1own[15]);
  __syncthreads();

  // ---- out2 = relu(pre2 @ W2 + b2); mean pool over kept nodes ----
  {
    const int ig = tid >> 6, h4 = tid & 63;
    float4 w2c[MIDC];
#pragma unroll
    for (int c = 0; c < MIDC; ++c) w2c[c] = *(const float4*)(W2 + c*HH + (h4 << 2));
    float4 bv = *(const float4*)(b2 + (h4 << 2));
    float4 pacc = make_float4(0.f, 0.f, 0.f, 0.f);
    for (int k = 0; k < 64; ++k) {
      int i = (ig << 6) + k;                 // wave-uniform -> LDS broadcasts
      if (ubv[i] == 0u) continue;
      float4 v0 = hb4[i*5+0], v1 = hb4[i*5+1], v2 = hb4[i*5+2], v3 = hb4[i*5+3];
      float vv[MIDC] = {v0.x,v0.y,v0.z,v0.w, v1.x,v1.y,v1.z,v1.w,
                        v2.x,v2.y,v2.z,v2.w, v3.x,v3.y,v3.z,v3.w};
      float t0 = bv.x, t1 = bv.y, t2 = bv.z, t3 = bv.w;
#pragma unroll
      for (int c = 0; c < MIDC; ++c) {
        t0 += vv[c]*w2c[c].x; t1 += vv[c]*w2c[c].y;
        t2 += vv[c]*w2c[c].z; t3 += vv[c]*w2c[c].w;
      }
      pacc.x += fmaxf(t0, 0.f); pacc.y += fmaxf(t1, 0.f);
      pacc.z += fmaxf(t2, 0.f); pacc.w += fmaxf(t3, 0.f);
    }
    float4* part4 = (float4*)(sm + OFF_CSR);           // reuse CSR space: [16][256]
    part4[(ig << 6) + h4] = pacc;
  }
  __syncthreads();
  if (tid < HH) {
    const float* part = sm + OFF_CSR;
    float s = 0.f;
#pragma unroll
    for (int ig = 0; ig < 16; ++ig) s += part[ig*HH + tid];
    emb[(size_t)g*HH + tid] = s * (1.0f/(float)KK);
  }
}

// ---------------------------------------------------------------------------
// Grid barrier (sense-reversal via generation counter), device scope.
// Cross-XCD visibility: __threadfence + agent-scope atomics.
// ---------------------------------------------------------------------------
__device__ __forceinline__ void grid_barrier(unsigned* bar, unsigned nblk) {
  __syncthreads();
  if (threadIdx.x == 0) {
    __threadfence();   // release h writes device-wide
    unsigned g0 = __hip_atomic_load(bar + 1, __ATOMIC_RELAXED, __HIP_MEMORY_SCOPE_AGENT);
    unsigned arr = __hip_atomic_fetch_add(bar, 1u, __ATOMIC_ACQ_REL, __HIP_MEMORY_SCOPE_AGENT);
    if (arr == nblk - 1u) {
      __hip_atomic_store(bar, 0u, __ATOMIC_RELAXED, __HIP_MEMORY_SCOPE_AGENT);
      __hip_atomic_fetch_add(bar + 1, 1u, __ATOMIC_RELEASE, __HIP_MEMORY_SCOPE_AGENT);
    } else {
      while (__hip_atomic_load(bar + 1, __ATOMIC_ACQUIRE, __HIP_MEMORY_SCOPE_AGENT) == g0)
        __builtin_amdgcn_s_sleep(8);
    }
    __threadfence();   // acquire: invalidate stale caches before reading h
  }
  __syncthreads();
}

// ---------------------------------------------------------------------------
// K2: fused LSTM input-proj + recurrence + classifier in ONE kernel.
// 256 blocks x 256 threads; block = (b = blk>>4, ug = blk&15).
// thread = (ul = tid>>4 unit-local, sub = tid&15 column-group of 16).
// W_ih rows (64 KB/block) then W_hh rows live in registers; 16 grid barriers.
// ---------------------------------------------------------------------------
__global__ __launch_bounds__(256) void k_lstm_all(
    const float* __restrict__ emb, const float* __restrict__ W_ih,
    const float* __restrict__ b_ih, const float* __restrict__ b_hh,
    const float* __restrict__ W_hh, const float* __restrict__ clsW,
    const float* __restrict__ clsb, float* __restrict__ hA,
    float* __restrict__ hB, unsigned* __restrict__ bar,
    float* __restrict__ out)
{
  __shared__ float Ablk[TT][4][16];
  __shared__ float redsc[4];
  const int bid = blockIdx.x, b = bid >> 4, ug = bid & 15;
  const int tid = threadIdx.x, ul = tid >> 4, sub = tid & 15;
  const int u = ug*16 + ul;

  // ---- phase A: A[t][g][ul] = emb[t,b] . W_ih[g*256+u] + biases ----
  {
    float4 wih[4][4];
#pragma unroll
    for (int g = 0; g < 4; ++g) {
      const float4* wr = (const float4*)(W_ih + (size_t)(g*HH + u)*HH) + sub*4;
#pragma unroll
      for (int k = 0; k < 4; ++k) wih[g][k] = wr[k];
    }
    for (int t = 0; t < TT; ++t) {
      const float4* e4 = (const float4*)(emb + (size_t)(t*BB + b)*HH) + sub*4;
      float4 e0 = e4[0], e1 = e4[1], e2 = e4[2], e3 = e4[3];
#pragma unroll
      for (int g = 0; g < 4; ++g) {
        float p = dot4(wih[g][0],e0) + dot4(wih[g][1],e1)
                + dot4(wih[g][2],e2) + dot4(wih[g][3],e3);
        p += __shfl_xor(p, 1); p += __shfl_xor(p, 2);
        p += __shfl_xor(p, 4); p += __shfl_xor(p, 8);
        if (sub == 0) Ablk[t][g][ul] = p + b_ih[g*HH + u] + b_hh[g*HH + u];
      }
    }
  }

  // ---- load W_hh rows into registers (after wih is dead) ----
  float4 whh[4][4];
#pragma unroll
  for (int g = 0; g < 4; ++g) {
    const float4* wr = (const float4*)(W_hh + (size_t)(g*HH + u)*HH) + sub*4;
#pragma unroll
    for (int k = 0; k < 4; ++k) whh[g][k] = wr[k];
  }
  __syncthreads();

  // ---- phase B: 16 recurrent steps with grid barriers ----
  float cst = 0.0f;
  for (int t = 0; t < TT; ++t) {
    float pg0 = 0.f, pg1 = 0.f, pg2 = 0.f, pg3 = 0.f;
    if (t > 0) {
      const float* hprev = (t & 1) ? hA : hB;    // t-1 even wrote hA
      const float4* h4 = (const float4*)(hprev + b*HH) + sub*4;
      float4 h0v = h4[0], h1v = h4[1], h2v = h4[2], h3v = h4[3];
      pg0 = dot4(whh[0][0],h0v)+dot4(whh[0][1],h1v)+dot4(whh[0][2],h2v)+dot4(whh[0][3],h3v);
      pg1 = dot4(whh[1][0],h0v)+dot4(whh[1][1],h1v)+dot4(whh[1][2],h2v)+dot4(whh[1][3],h3v);
      pg2 = dot4(whh[2][0],h0v)+dot4(whh[2][1],h1v)+dot4(whh[2][2],h2v)+dot4(whh[2][3],h3v);
      pg3 = dot4(whh[3][0],h0v)+dot4(whh[3][1],h1v)+dot4(whh[3][2],h2v)+dot4(whh[3][3],h3v);
#pragma unroll
      for (int off = 1; off < 16; off <<= 1) {
        pg0 += __shfl_xor(pg0, off); pg1 += __shfl_xor(pg1, off);
        pg2 += __shfl_xor(pg2, off); pg3 += __shfl_xor(pg3, off);
      }
    }
    if (sub == 0) {
      float gi = pg0 + Ablk[t][0][ul];
      float gf = pg1 + Ablk[t][1][ul];
      float gn = pg2 + Ablk[t][2][ul];
      float go = pg3 + Ablk[t][3][ul];
      float iv = 1.0f/(1.0f + expf(-gi));
      float fv = 1.0f/(1.0f + expf(-gf));
      float gv = tanhf(gn);
      float ov = 1.0f/(1.0f + expf(-go));
      cst = fv*cst + iv*gv;
      float* hw = (t & 1) ? hB : hA;
      hw[b*HH + u] = ov * tanhf(cst);
    }
    grid_barrier(bar, 256u);
  }

  // ---- classifier (blocks with ug==0): out[b] = h_final . clsW + clsb ----
  if (ug == 0) {
    float p = hB[b*HH + tid] * clsW[tid];      // t=15 (odd) wrote hB
#pragma unroll
    for (int off = 32; off >= 1; off >>= 1) p += __shfl_down(p, off);
    if ((tid & 63) == 0) redsc[tid >> 6] = p;
    __syncthreads();
    if (tid == 0) out[b] = redsc[0] + redsc[1] + redsc[2] + redsc[3] + clsb[0];
  }
}

// ---------------------------------------------------------------------------
extern "C" void kernel_launch(void* const* d_in, const int* in_sizes, int n_in,
                              void* d_out, int out_size, void* d_ws, size_t ws_size,
                              hipStream_t stream)
{
  const float* x    = (const float*)d_in[0];
  const int*   ei   = (const int*)  d_in[1];
  const float* W1   = (const float*)d_in[2];
  const float* b1   = (const float*)d_in[3];
  const float* Wl   = (const float*)d_in[4];
  const float* Wr   = (const float*)d_in[5];
  const float* bs   = (const float*)d_in[6];
  const float* W2   = (const float*)d_in[7];
  const float* b2   = (const float*)d_in[8];
  const float* Wih  = (const float*)d_in[9];
  const float* Whh  = (const float*)d_in[10];
  const float* bih  = (const float*)d_in[11];
  const float* bhh  = (const float*)d_in[12];
  const float* clsW = (const float*)d_in[13];
  const float* clsb = (const float*)d_in[14];
  float* out = (float*)d_out;

  // ws layout: h0 (bf16x16/node, 8 MB) | emb (256 KB) | hA | hB | barrier
  unsigned* h0  = (unsigned*)d_ws;                       // [256*1024][8] uints
  float*    emb = (float*)(h0 + (size_t)TT*BB*NN*8);     // [T*B][256]
  float*    hA  = emb + (size_t)TT*BB*HH;                // [16][256]
  float*    hB  = hA + BB*HH;                            // [16][256]
  unsigned* bar = (unsigned*)(hB + BB*HH);               // [2]

  (void)hipFuncSetAttribute(reinterpret_cast<const void*>(k_graph),
      hipFuncAttributeMaxDynamicSharedMemorySize, SM_BYTES);

  (void)hipMemsetAsync(bar, 0, 2*sizeof(unsigned), stream);
  hipLaunchKernelGGL(k_conv1, dim3(TT*BB*NN/256), dim3(256), 0, stream,
                     x, W1, h0);
  hipLaunchKernelGGL(k_graph, dim3(TT*BB), dim3(1024), SM_BYTES, stream,
                     h0, ei, b1, Wl, Wr, bs, W2, b2, emb);
  hipLaunchKernelGGL(k_lstm_all, dim3(256), dim3(256), 0, stream,
                     emb, Wih, bih, bhh, Whh, clsW, clsb, hA, hB, bar, out);
}